// Round 10
// baseline (252.158 us; speedup 1.0000x reference)
//
#include <hip/hip_runtime.h>
#include <hip/hip_bf16.h>

// DualEmbedding v10 — v9 + (1) node grid 512->1568 (was 2 blocks/CU; LDS-W
// node kernel needs full CU coverage), (2) f32->bf16 via __float2bfloat16 so
// the compiler emits native v_cvt_pk_bf16_f32 (manual bit-twiddle was 3 VALU
// per element). Edge kernel structure unchanged from v9 (champion, 247us).
//
// Kernel A (node): h_node_bf16[node]: chunk(g,k) at byte k*64+g*16 holds
//   dims {16*(2k)+4g+j, 16*(2k+1)+4g+j}, j=0..3 (bf16).
// Kernel B (edge): out = LN(x_edge @ W_edge.T + b_edge + 0.5*(h[src]+h[dst]))
//
// MFMA mapping (16x16x32 bf16): C tile t, lane(c=lane&15,g=lane>>4), reg j =
//   C[dim=16t+4g+j][row base+c]  -> each lane owns all 128 dims of ONE row.
// LDS W layout: row r, 8-bf16 slot sigma stored at sigma^(r&7) — measured 0
// bank conflicts (R4/R6).

typedef __attribute__((ext_vector_type(8))) short bf16x8;
typedef __attribute__((ext_vector_type(4))) float f32x4;

__device__ __forceinline__ short f2bf(float f) {          // RTNE via HW cvt
  __hip_bfloat16 h = __float2bfloat16(f);
  return *reinterpret_cast<short*>(&h);
}
__device__ __forceinline__ float bf2f(short s) {
  return __uint_as_float(((unsigned)(unsigned short)s) << 16);
}
__device__ __forceinline__ bf16x8 cvt8(const float* __restrict__ p) {
  const f32x4 a = *(const f32x4*)p;
  const f32x4 b = *(const f32x4*)(p + 4);
  bf16x8 r;
  r[0] = f2bf(a[0]); r[1] = f2bf(a[1]); r[2] = f2bf(a[2]); r[3] = f2bf(a[3]);
  r[4] = f2bf(b[0]); r[5] = f2bf(b[1]); r[6] = f2bf(b[2]); r[7] = f2bf(b[3]);
  return r;
}

// ---------------- node projection -> permuted bf16 table -------------------
__global__ __launch_bounds__(256) void node_mfma_kernel(
    const float* __restrict__ x_node,
    const float* __restrict__ W_node,
    const float* __restrict__ b_node,
    short* __restrict__ h_node,          // [N][128] bf16, (k,g)-chunked
    int n_nodes)
{
  __shared__ short Wlds[16384];         // 128 rows x 128 bf16 = 32 KB, swizzled
  __shared__ float blds[128];

  const int tid = threadIdx.x;
  {
    const int r = tid >> 1, h = tid & 1;      // row, which 64-col half
    const float* wr = W_node + (size_t)r * 128 + 64 * h;
#pragma unroll
    for (int q = 0; q < 8; ++q) {
      const bf16x8 v = cvt8(wr + 8 * q);
      const int slot = (8 * h + q) ^ (r & 7);
      *(bf16x8*)(&Wlds[r * 128 + slot * 8]) = v;
    }
    if (tid < 128) blds[tid] = b_node[tid];
  }
  __syncthreads();

  const int lane = tid & 63;
  const int c = lane & 15, g = lane >> 4;
  const int gw = blockIdx.x * 4 + (tid >> 6);
  const int nw = gridDim.x * 4;
  const int ntiles = (n_nodes + 15) >> 4;

  int woff[4];
#pragma unroll
  for (int s = 0; s < 4; ++s) woff[s] = c * 128 + ((4 * s + g) ^ (c & 7)) * 8;

  for (int tile = gw; tile < ntiles; tile += nw) {
    const int n0 = tile << 4;
    const int n = (n0 + c < n_nodes) ? n0 + c : n_nodes - 1;
    const float* xr = x_node + (size_t)n * 128;
    bf16x8 bx[4];
#pragma unroll
    for (int s = 0; s < 4; ++s) bx[s] = cvt8(xr + 32 * s + 8 * g);

    f32x4 acc[8];
#pragma unroll
    for (int t = 0; t < 8; ++t)
      acc[t] = *(const f32x4*)(blds + 16 * t + 4 * g);
#pragma unroll
    for (int t = 0; t < 8; ++t)
#pragma unroll
      for (int s = 0; s < 4; ++s) {
        const bf16x8 a = *(const bf16x8*)(&Wlds[t * 2048 + woff[s]]);
        acc[t] = __builtin_amdgcn_mfma_f32_16x16x32_bf16(a, bx[s], acc[t], 0, 0, 0);
      }

    if (n0 + c < n_nodes) {
      short* o = h_node + (size_t)(n0 + c) * 128 + g * 8;
#pragma unroll
      for (int k = 0; k < 4; ++k) {
        bf16x8 v;
#pragma unroll
        for (int j = 0; j < 4; ++j) {
          v[j]     = f2bf(acc[2 * k][j]);
          v[4 + j] = f2bf(acc[2 * k + 1][j]);
        }
        *(bf16x8*)(o + 32 * k) = v;
      }
    }
  }
}

// ---------------- fused edge: GEMM + gather + LayerNorm --------------------
__global__ __launch_bounds__(256) void edge_mfma_kernel(
    const float* __restrict__ x_edge,
    const int*   __restrict__ eidx,      // [2, E] int32
    const float* __restrict__ W_edge,
    const float* __restrict__ b_edge,
    const short* __restrict__ h_node,    // permuted bf16, (k,g)-chunked
    const float* __restrict__ gamma,
    const float* __restrict__ beta,
    float* __restrict__ out,
    int n_edges)
{
  __shared__ short Wlds[8192];          // 128 rows x 64 bf16 = 16 KB, swizzled
  __shared__ float plds[384];           // bias | gamma | beta

  const int tid = threadIdx.x;
  {
    const int r = tid >> 1, h = tid & 1;
    const float* wr = W_edge + (size_t)r * 64 + 32 * h;
#pragma unroll
    for (int q = 0; q < 4; ++q) {
      const bf16x8 v = cvt8(wr + 8 * q);
      const int slot = (4 * h + q) ^ (r & 7);
      *(bf16x8*)(&Wlds[r * 64 + slot * 8]) = v;
    }
    if (tid < 128) {
      plds[tid]       = b_edge[tid];
      plds[128 + tid] = gamma[tid];
      plds[256 + tid] = beta[tid];
    }
  }
  __syncthreads();

  const int lane = tid & 63;
  const int c = lane & 15, g = lane >> 4;
  const int gw = blockIdx.x * 4 + (tid >> 6);
  const int nw = gridDim.x * 4;
  const int ntiles = (n_edges + 15) >> 4;

  const int w0off = c * 64 + ((g) ^ (c & 7)) * 8;
  const int w1off = c * 64 + ((4 + g) ^ (c & 7)) * 8;

  if (gw >= ntiles) return;

  auto LOADIDX = [&](int tile, int& src, int& dst) {
    const int e = (tile * 16 + c < n_edges) ? tile * 16 + c : n_edges - 1;
    src = eidx[e];
    dst = eidx[n_edges + e];
  };
  auto LOADX = [&](int tile, bf16x8& b0, bf16x8& b1) {
    const int e = (tile * 16 + c < n_edges) ? tile * 16 + c : n_edges - 1;
    const float* xr = x_edge + (size_t)e * 64;
    b0 = cvt8(xr + 8 * g);
    b1 = cvt8(xr + 32 + 8 * g);
  };
  auto GATHER = [&](int src, int dst, bf16x8* vs, bf16x8* vd) {
    const short* hs = h_node + (size_t)src * 128 + g * 8;
    const short* hd = h_node + (size_t)dst * 128 + g * 8;
#pragma unroll
    for (int k = 0; k < 4; ++k) {
      vs[k] = *(const bf16x8*)(hs + 32 * k);
      vd[k] = *(const bf16x8*)(hd + 32 * k);
    }
  };

  // ---- pipeline state (single-buffered gathers) -------------------------
  bf16x8 bx0, bx1, bxN0, bxN1;
  bf16x8 vs[4], vd[4];
  int srcN, dstN;

  {
    int src0, dst0;
    LOADIDX(gw, src0, dst0);
    LOADX(gw, bx0, bx1);
    GATHER(src0, dst0, vs, vd);
    LOADIDX(gw + nw, srcN, dstN);
  }

  for (int t = gw; t < ntiles; t += nw) {
    // 1) fold tile-t gathers into acc init (issued one iteration ago)
    f32x4 acc[8];
#pragma unroll
    for (int k = 0; k < 4; ++k)
#pragma unroll
      for (int j = 0; j < 4; ++j) {
        acc[2 * k][j]     = plds[16 * (2 * k) + 4 * g + j]
                          + 0.5f * (bf2f(vs[k][j]) + bf2f(vd[k][j]));
        acc[2 * k + 1][j] = plds[16 * (2 * k + 1) + 4 * g + j]
                          + 0.5f * (bf2f(vs[k][4 + j]) + bf2f(vd[k][4 + j]));
      }

    // 2) reuse freed vs/vd: issue gathers for tile t+nw
    GATHER(srcN, dstN, vs, vd);
    // 3) prefetch idx for t+2nw and x for t+nw
    LOADIDX(t + 2 * nw, srcN, dstN);
    LOADX(t + nw, bxN0, bxN1);

    // 4) GEMM for tile t (A from swizzled LDS)
#pragma unroll
    for (int tt = 0; tt < 8; ++tt) {
      const bf16x8 a0 = *(const bf16x8*)(&Wlds[tt * 1024 + w0off]);
      const bf16x8 a1 = *(const bf16x8*)(&Wlds[tt * 1024 + w1off]);
      acc[tt] = __builtin_amdgcn_mfma_f32_16x16x32_bf16(a0, bx0, acc[tt], 0, 0, 0);
      acc[tt] = __builtin_amdgcn_mfma_f32_16x16x32_bf16(a1, bx1, acc[tt], 0, 0, 0);
    }

    // 5) LayerNorm (dims of one edge split over lanes c, c+16, c+32, c+48)
    float s1 = 0.f;
#pragma unroll
    for (int tt = 0; tt < 8; ++tt)
      s1 += (acc[tt][0] + acc[tt][1]) + (acc[tt][2] + acc[tt][3]);
    s1 += __shfl_xor(s1, 16, 64);
    s1 += __shfl_xor(s1, 32, 64);
    const float mu = s1 * (1.f / 128.f);

    float s2 = 0.f;
#pragma unroll
    for (int tt = 0; tt < 8; ++tt)
#pragma unroll
      for (int j = 0; j < 4; ++j) {
        const float d = acc[tt][j] - mu;
        acc[tt][j] = d;
        s2 = fmaf(d, d, s2);
      }
    s2 += __shfl_xor(s2, 16, 64);
    s2 += __shfl_xor(s2, 32, 64);
    const float rstd = rsqrtf(s2 * (1.f / 128.f) + 1e-5f);

    // 6) store
    if (t * 16 + c < n_edges) {
      float* o = out + (size_t)(t * 16 + c) * 128 + 4 * g;
#pragma unroll
      for (int tt = 0; tt < 8; ++tt) {
        f32x4 r;
#pragma unroll
        for (int j = 0; j < 4; ++j)
          r[j] = fmaf(acc[tt][j] * rstd, plds[128 + 16 * tt + 4 * g + j],
                      plds[256 + 16 * tt + 4 * g + j]);
        *(f32x4*)(o + 16 * tt) = r;
      }
    }

    // 7) rotate x prefetch
    bx0 = bxN0; bx1 = bxN1;
  }
}

extern "C" void kernel_launch(void* const* d_in, const int* in_sizes, int n_in,
                              void* d_out, int out_size, void* d_ws, size_t ws_size,
                              hipStream_t stream) {
  const float* x_node = (const float*)d_in[0];
  const float* x_edge = (const float*)d_in[1];
  const int*   eidx   = (const int*)  d_in[2];
  const float* W_edge = (const float*)d_in[3];
  const float* b_edge = (const float*)d_in[4];
  const float* W_node = (const float*)d_in[5];
  const float* b_node = (const float*)d_in[6];
  const float* gamma  = (const float*)d_in[7];
  const float* beta   = (const float*)d_in[8];
  float* out = (float*)d_out;

  const int n_nodes = in_sizes[0] / 128;
  const int n_edges = in_sizes[2] / 2;

  short* h_node = (short*)d_ws;
  if (ws_size < (size_t)n_nodes * 128 * sizeof(short)) return;  // ws too small

  // node: ntiles = 6250; 1568 blocks x 4 waves ~= 1 tile/wave, all CUs busy
  node_mfma_kernel<<<1568, 256, 0, stream>>>(x_node, W_node, b_node, h_node, n_nodes);
  edge_mfma_kernel<<<2048, 256, 0, stream>>>(x_edge, eidx, W_edge, b_edge,
                                             h_node, gamma, beta, out, n_edges);
}